// Round 1
// baseline (6275.371 us; speedup 1.0000x reference)
//
#include <hip/hip_runtime.h>
#include <cstdint>
#include <cstddef>

#define HH 512
#define BB 64
#define TT 256
#define GG 2048   // 4*HH
#define NCLS 50257

__device__ __forceinline__ float sigmoidf_(float x){ return 1.f/(1.f + expf(-x)); }

// GEMM: out[(t*BB+b)][n] = sum_k A_row[k]*Bw[n][k] + bias1[n] + bias2[n]
// where global row r = row0+... maps r=(b*TT+t), A_row = gather ? emb[gather[r]] : A[r].
// M=16384, N=2048, K=512. Tiles 128x128, BK=32, 256 threads, 8x8 per thread.
__global__ __launch_bounds__(256,2) void gemm_xg(
    const float* __restrict__ A, const int* __restrict__ gather,
    const float* __restrict__ Bw, const float* __restrict__ bias1,
    const float* __restrict__ bias2, float* __restrict__ out, int K)
{
    __shared__ float As[32][132];
    __shared__ float Bs[32][132];
    const int tid = threadIdx.x;
    const int row0 = blockIdx.y * 128, col0 = blockIdx.x * 128;
    const int tx = tid & 15, ty = tid >> 4;
    float acc[8][8];
    #pragma unroll
    for (int i=0;i<8;i++)
        #pragma unroll
        for (int j=0;j<8;j++) acc[i][j]=0.f;

    for (int k0=0;k0<K;k0+=32){
        #pragma unroll
        for (int i=0;i<4;i++){
            int f = tid + i*256;            // float4 index in [0,1024)
            int r = f>>3, kq = f&7;         // 8 float4 per row
            const int grow = row0 + r;
            const float* src = gather ? (A + (size_t)gather[grow]*K)
                                      : (A + (size_t)grow*K);
            float4 v = *(const float4*)(src + k0 + kq*4);
            As[kq*4+0][r]=v.x; As[kq*4+1][r]=v.y; As[kq*4+2][r]=v.z; As[kq*4+3][r]=v.w;
        }
        #pragma unroll
        for (int i=0;i<4;i++){
            int f = tid + i*256;
            int r = f>>3, kq = f&7;
            const float* src = Bw + (size_t)(col0 + r)*K;
            float4 v = *(const float4*)(src + k0 + kq*4);
            Bs[kq*4+0][r]=v.x; Bs[kq*4+1][r]=v.y; Bs[kq*4+2][r]=v.z; Bs[kq*4+3][r]=v.w;
        }
        __syncthreads();
        #pragma unroll
        for (int kk=0;kk<32;kk++){
            float4 a03 = *(float4*)&As[kk][ty*8];
            float4 a47 = *(float4*)&As[kk][ty*8+4];
            float4 b03 = *(float4*)&Bs[kk][tx*8];
            float4 b47 = *(float4*)&Bs[kk][tx*8+4];
            float a[8] = {a03.x,a03.y,a03.z,a03.w,a47.x,a47.y,a47.z,a47.w};
            float b[8] = {b03.x,b03.y,b03.z,b03.w,b47.x,b47.y,b47.z,b47.w};
            #pragma unroll
            for (int i=0;i<8;i++)
                #pragma unroll
                for (int j=0;j<8;j++) acc[i][j] += a[i]*b[j];
        }
        __syncthreads();
    }
    #pragma unroll
    for (int i=0;i<8;i++){
        int r = row0 + ty*8 + i;
        int b = r >> 8, t = r & 255;        // r = b*256 + t
        float* orow = out + (size_t)(t*BB + b)*GG + col0 + tx*8;
        #pragma unroll
        for (int j=0;j<8;j++){
            int col = col0 + tx*8 + j;
            orow[j] = acc[i][j] + bias1[col] + bias2[col];
        }
    }
}

// One recurrent step. 256 wgs; wg owns h-dims {j0, j0+1} -> 8 gate rows
// (rows gb*512 + j0 + {0,1} for gb=0..3). Weight slice (8x512) staged in LDS.
// threads: tid = q*64+b, q = k-quarter, b = batch. Partials reduced via LDS.
__global__ __launch_bounds__(256) void lstm_step(
    const float* __restrict__ xg_t,   // [BB][GG] for this t
    const float* __restrict__ Whh,    // [GG][HH]
    const float* __restrict__ h_in,   // [BB][HH]
    float* __restrict__ c,            // [BB][HH] in-place (own slice only)
    float* __restrict__ h_out,        // [BB][HH]
    float* __restrict__ hseq)         // h0seq + t*HH (stride TT*HH per b) or null
{
    __shared__ float Wl[8][HH];        // 16 KB
    __shared__ float part[4][BB][8];   // 8 KB
    const int tid = threadIdx.x;
    const int j0 = blockIdx.x * 2;

    #pragma unroll
    for (int i=0;i<4;i++){
        int f = tid + i*256;           // float4 idx over 8 rows * 128
        int r = f>>7, k4 = f&127;
        int grow = (r>>1)*HH + j0 + (r&1);
        *(float4*)&Wl[r][k4*4] = *(const float4*)(Whh + (size_t)grow*HH + k4*4);
    }
    __syncthreads();
    {
        const int q = tid>>6, b = tid&63;
        const float* hp = h_in + b*HH + q*128;
        float pr[8] = {0,0,0,0,0,0,0,0};
        #pragma unroll 4
        for (int k4=0;k4<32;k4++){
            float4 hv = *(const float4*)(hp + k4*4);
            #pragma unroll
            for (int r=0;r<8;r++){
                float4 wv = *(const float4*)&Wl[r][q*128 + k4*4];
                pr[r] += hv.x*wv.x + hv.y*wv.y + hv.z*wv.z + hv.w*wv.w;
            }
        }
        #pragma unroll
        for (int r=0;r<8;r++) part[q][b][r] = pr[r];
    }
    __syncthreads();
    if (tid < BB){
        const int b = tid;
        float gs[8];
        #pragma unroll
        for (int r=0;r<8;r++){
            gs[r] = part[0][b][r] + part[1][b][r] + part[2][b][r] + part[3][b][r]
                  + xg_t[(size_t)b*GG + (r>>1)*HH + j0 + (r&1)];
        }
        float i0 = sigmoidf_(gs[0]), i1 = sigmoidf_(gs[1]);
        float f0 = sigmoidf_(gs[2]), f1 = sigmoidf_(gs[3]);
        float g0 = tanhf(gs[4]),     g1 = tanhf(gs[5]);
        float o0 = sigmoidf_(gs[6]), o1 = sigmoidf_(gs[7]);
        float c0 = c[b*HH + j0], c1 = c[b*HH + j0 + 1];
        c0 = f0*c0 + i0*g0;  c1 = f1*c1 + i1*g1;
        c[b*HH + j0] = c0;   c[b*HH + j0 + 1] = c1;
        float h0 = o0*tanhf(c0), h1 = o1*tanhf(c1);
        h_out[b*HH + j0] = h0;  h_out[b*HH + j0 + 1] = h1;
        if (hseq){
            hseq[(size_t)b*TT*HH + j0]     = h0;
            hseq[(size_t)b*TT*HH + j0 + 1] = h1;
        }
    }
}

// logits: out[b][v] = sum_k h[b][k]*W[v][k] + bias[v]; M=64, N=50257, K=512
__global__ __launch_bounds__(256) void gemm_logits(
    const float* __restrict__ hlast, const float* __restrict__ W,
    const float* __restrict__ bias, float* __restrict__ out)
{
    __shared__ float As[32][68];
    __shared__ float Bs[32][68];
    const int tid = threadIdx.x;
    const int col0 = blockIdx.x * 64;
    const int tx = tid & 15, ty = tid >> 4;
    float acc[4][4];
    #pragma unroll
    for (int i=0;i<4;i++)
        #pragma unroll
        for (int j=0;j<4;j++) acc[i][j]=0.f;

    for (int k0=0;k0<HH;k0+=32){
        #pragma unroll
        for (int i=0;i<2;i++){
            int f = tid + i*256;       // [0,512)
            int r = f>>3, kq = f&7;
            float4 v = *(const float4*)(hlast + (size_t)r*HH + k0 + kq*4);
            As[kq*4+0][r]=v.x; As[kq*4+1][r]=v.y; As[kq*4+2][r]=v.z; As[kq*4+3][r]=v.w;
        }
        #pragma unroll
        for (int i=0;i<2;i++){
            int f = tid + i*256;
            int r = f>>3, kq = f&7;
            int vrow = col0 + r;
            float4 v = make_float4(0.f,0.f,0.f,0.f);
            if (vrow < NCLS) v = *(const float4*)(W + (size_t)vrow*HH + k0 + kq*4);
            Bs[kq*4+0][r]=v.x; Bs[kq*4+1][r]=v.y; Bs[kq*4+2][r]=v.z; Bs[kq*4+3][r]=v.w;
        }
        __syncthreads();
        #pragma unroll
        for (int kk=0;kk<32;kk++){
            float4 a4 = *(float4*)&As[kk][ty*4];
            float4 b4 = *(float4*)&Bs[kk][tx*4];
            float a[4] = {a4.x,a4.y,a4.z,a4.w};
            float b[4] = {b4.x,b4.y,b4.z,b4.w};
            #pragma unroll
            for (int i=0;i<4;i++)
                #pragma unroll
                for (int j=0;j<4;j++) acc[i][j] += a[i]*b[j];
        }
        __syncthreads();
    }
    #pragma unroll
    for (int i=0;i<4;i++){
        int b = ty*4 + i;
        #pragma unroll
        for (int j=0;j<4;j++){
            int v = col0 + tx*4 + j;
            if (v < NCLS) out[(size_t)b*NCLS + v] = acc[i][j] + bias[v];
        }
    }
}

extern "C" void kernel_launch(void* const* d_in, const int* in_sizes, int n_in,
                              void* d_out, int out_size, void* d_ws, size_t ws_size,
                              hipStream_t stream)
{
    const int*   X     = (const int*)  d_in[0];
    const float* emb   = (const float*)d_in[1];
    const float* w_ih0 = (const float*)d_in[2];
    const float* w_hh0 = (const float*)d_in[3];
    const float* b_ih0 = (const float*)d_in[4];
    const float* b_hh0 = (const float*)d_in[5];
    const float* w_ih1 = (const float*)d_in[6];
    const float* w_hh1 = (const float*)d_in[7];
    const float* b_ih1 = (const float*)d_in[8];
    const float* b_hh1 = (const float*)d_in[9];
    const float* Wout  = (const float*)d_in[10];
    const float* bout  = (const float*)d_in[11];
    float* out = (float*)d_out;

    float* ws    = (float*)d_ws;
    float* xg    = ws;                  // [TT][BB][GG] = 33,554,432 floats (134 MB)
    float* h0seq = ws + 33554432;       // [BB][TT][HH] = 8,388,608 floats (33.5 MB)
    float* hA    = ws + 41943040;       // [BB][HH]
    float* hB    = ws + 41975808;       // [BB][HH]
    float* cst   = ws + 42008576;       // [BB][HH]
    // total 42,041,344 floats = 168.2 MB of d_ws

    dim3 gemmGrid(16, 128);   // N/128, M/128

    // ---- layer 0: xg0 = gather(emb,X) @ w_ih0^T + b_ih0 + b_hh0
    gemm_xg<<<gemmGrid, 256, 0, stream>>>(emb, X, w_ih0, b_ih0, b_hh0, xg, HH);
    hipMemsetAsync(hA, 0, 3*BB*HH*sizeof(float), stream);   // hA, hB, c
    for (int t=0;t<TT;t++){
        const float* hin = (t&1) ? hB : hA;
        float*       hout= (t&1) ? hA : hB;
        lstm_step<<<256, 256, 0, stream>>>(xg + (size_t)t*BB*GG, w_hh0, hin, cst, hout,
                                           h0seq + (size_t)t*HH);
    }
    // ---- layer 1: xg1 = h0seq @ w_ih1^T + b_ih1 + b_hh1   (overwrite xg)
    gemm_xg<<<gemmGrid, 256, 0, stream>>>(h0seq, nullptr, w_ih1, b_ih1, b_hh1, xg, HH);
    hipMemsetAsync(hA, 0, 3*BB*HH*sizeof(float), stream);
    for (int t=0;t<TT;t++){
        const float* hin = (t&1) ? hB : hA;
        float*       hout= (t&1) ? hA : hB;
        lstm_step<<<256, 256, 0, stream>>>(xg + (size_t)t*BB*GG, w_hh1, hin, cst, hout,
                                           nullptr);
    }
    // t=255 wrote hA -> final hidden state
    gemm_logits<<<786, 256, 0, stream>>>(hA, Wout, bout, out);
}